// Round 12
// baseline (100.151 us; speedup 1.0000x reference)
//
#include <hip/hip_runtime.h>
#include <hip/hip_bf16.h>

typedef __attribute__((ext_vector_type(8)))  short short8;
typedef __attribute__((ext_vector_type(4)))  float f32x4;
typedef __attribute__((ext_vector_type(16))) float f32x16;

#define CIN   16
#define HH    256
#define WW    256
#define OHH   254
#define OWW   254
#define HW    (HH * WW)            // 65536: ci-plane stride (dwords)

// Chunk region (region-relative): [8 rowslots][36 w][16 ci] fp32.
// ROWB = 36*64 = 2304 B (multiple of 256 -> row part never feeds swizzle bits).
// Swizzle flips byte bits 4-5: S = L ^ (((L>>6)&3)<<4), (L>>6)&3 == w&3.
// RULE: offsets must be XORed AFTER addition of any sub-cell displacement
// (R11 bug: (c^X)+16 carried through bit 5 for odd w; correct is (c+16)^X).
#define ROWB   2304
#define CHUNKB 18432

#define GLOAD4(gp, lp) __builtin_amdgcn_global_load_lds( \
    (const __attribute__((address_space(1))) void*)(gp), \
    (__attribute__((address_space(3))) void*)(lp), 4, 0, 0)

// fast tanh(tanh(x)): exp2-based (verified absmax 3.9e-3 in R1-R10)
__device__ __forceinline__ float dtanh2(float x) {
    const float K = 2.8853900817779268f;   // 2*log2(e)
    float xc = fminf(fmaxf(x, -9.0f), 9.0f);
    float e1 = __builtin_amdgcn_exp2f(K * xc);
    float t1 = 1.0f - 2.0f * __builtin_amdgcn_rcpf(e1 + 1.0f);
    float e2 = __builtin_amdgcn_exp2f(K * t1);
    return 1.0f - 2.0f * __builtin_amdgcn_rcpf(e2 + 1.0f);
}

__device__ __forceinline__ ushort f2bf(float f) {
    unsigned u = __builtin_bit_cast(unsigned, f);
    unsigned r = (u + 0x7fffu + ((u >> 16) & 1u)) >> 16;
    return (ushort)r;
}

// Weights fp32 OIHW [64][16][3][3] -> 32x32x16 A-fragments (R9-proven):
// wfrag[tap][j][lane][r]: channel row = j*32+(lane&31), ci = 8*(lane>>5)+r.
__global__ void prep_weights(const float* __restrict__ wsrc, ushort* __restrict__ wfrag) {
    int idx = blockIdx.x * 256 + threadIdx.x;
    if (idx >= 9216) return;
    int r    = idx & 7;
    int lane = (idx >> 3) & 63;
    int j    = (idx >> 9) & 1;
    int tap  = idx >> 10;                 // 0..8
    int ci   = 8 * (lane >> 5) + r;
    int co   = j * 32 + (lane & 31);
    int kh   = tap / 3, kw = tap - 3 * kh;
    wfrag[idx] = f2bf(wsrc[(co * CIN + ci) * 9 + kh * 3 + kw]);
}

// DMA staging costs 0 VGPRs (global_load_lds); working set ~190 regs at
// (256,2). R2/R6/R10 lesson: register-prefetch spills; DMA prefetch cannot.
__global__ __launch_bounds__(256, 2) void conv_min_tanh(
        const float* __restrict__ x, const ushort* __restrict__ wfrag,
        const float* __restrict__ bias, float* __restrict__ out) {
    __shared__ __attribute__((aligned(64))) char lds[3 * CHUNKB];

    const int tid  = threadIdx.x;
    const int lane = tid & 63;
    const int wid  = tid >> 6;
    const int n    = blockIdx.z;
    const int oh0  = blockIdx.y * 32;
    const int ow0  = blockIdx.x * 32;
    const float* xb = x + ((size_t)n << 20);           // n*CIN*HW

    // ---- precompute per-lane DMA source offsets (region-relative, reusable) ----
    // pk = rowslot<<24 | ci<<16 | wg     (global dword = ci*65536 + hg*256 + wg)
    auto decode = [&](int o) -> unsigned {
        int b  = o * 4;
        int L  = b ^ (((b >> 6) & 3) << 4);            // inverse swizzle (involution)
        int rs = L / ROWB;
        int rem = L - rs * ROWB;
        int w  = rem >> 6;
        int ci = (rem & 63) >> 2;
        int wg = min(ow0 + w, WW - 1);                 // w 34,35 are pad cells (never read)
        return ((unsigned)rs << 24) | ((unsigned)ci << 16) | (unsigned)wg;
    };
    unsigned pkk[18];
#pragma unroll
    for (int k = 0; k < 18; ++k)
        pkk[k] = decode((wid * 18 + k) * 64 + lane);
    // mini region (image rows 0,1): 18 iters split {5,5,4,4} across waves
    const int mstart = wid * 5 - (wid > 2 ? 1 : 0) - (wid > 3 ? 1 : 0); // {0,5,10,14}
    const int mcnt   = (wid < 2) ? 5 : 4;
    unsigned pmini[5];
#pragma unroll
    for (int k = 0; k < 5; ++k)
        pmini[k] = decode((mstart + min(k, mcnt - 1)) * 64 + lane);

    // refill chunk c (patch rows 8c+2 .. 8c+9) into buf[c%3]
    auto refill = [&](int c) {
        const int rowbase = oh0 + 8 * c + 2;
        char* lbase = lds + (c % 3) * CHUNKB + wid * 4608;
#pragma unroll
        for (int k = 0; k < 18; ++k) {
            unsigned pk = pkk[k];
            int hg = min(rowbase + (int)(pk >> 24), HH - 1);
            const float* g = xb + ((pk & 0xFFFFFFu) + (hg << 8));
            GLOAD4(g, lbase + k * 256);
        }
    };

    // ---- prologue DMA: chunk0 -> buf0, rows 0..1 -> buf2 slots 0,1 ----
    refill(0);
    {
        char* lbase = lds + 2 * CHUNKB + mstart * 256;
#pragma unroll
        for (int k = 0; k < 5; ++k) {
            if (k < mcnt) {
                unsigned pk = pmini[k];
                int hg = oh0 + (int)(pk >> 24);        // rows 0,1: no clamp needed
                const float* g = xb + ((pk & 0xFFFFFFu) + (hg << 8));
                GLOAD4(g, lbase + k * 256);
            }
        }
    }

    // ---- weights (A-operand) + bias while DMA flies ----
    const int px    = lane & 31;
    const int khalf = lane >> 5;
    short8 wf[9][2];
#pragma unroll
    for (int tap = 0; tap < 9; ++tap) {
        wf[tap][0] = *reinterpret_cast<const short8*>(wfrag + ((tap * 2 + 0) * 64 + lane) * 8);
        wf[tap][1] = *reinterpret_cast<const short8*>(wfrag + ((tap * 2 + 1) * 64 + lane) * 8);
    }
    f32x16 bi0, bi1;                                    // D row = (r&3)+8*(r>>2)+4*khalf
#pragma unroll
    for (int q4 = 0; q4 < 4; ++q4) {
        f32x4 b0 = *reinterpret_cast<const f32x4*>(bias +  0 + 4 * khalf + 8 * q4);
        f32x4 b1 = *reinterpret_cast<const f32x4*>(bias + 32 + 4 * khalf + 8 * q4);
#pragma unroll
        for (int s = 0; s < 4; ++s) { bi0[q4 * 4 + s] = b0[s]; bi1[q4 * 4 + s] = b1[s]; }
    }
    // swizzled column offsets (bytes) per kw: lo and hi 16B of the 32B ci-half.
    // Swizzle AFTER the +16 (R11 bug: carry through swizzled bits for odd w).
    int colv[3], colh[3];
#pragma unroll
    for (int kw = 0; kw < 3; ++kw) {
        int c = (px + kw) * 64 + khalf * 32;
        int X = ((px + kw) & 3) << 4;
        colv[kw] = c ^ X;
        colh[kw] = (c + 16) ^ X;
    }

    asm volatile("s_waitcnt vmcnt(0)" ::: "memory");
    __syncthreads();                                    // chunk0 + mini ready

    // ---- quarter loop: refill(q+1) async || compute(q); one barrier/quarter ----
#pragma unroll
    for (int q = 0; q < 4; ++q) {
        if (q < 3) refill(q + 1);                       // 0-register prefetch, in flight

        const char* curb  = lds + (q % 3) * CHUNKB;
        const char* prevb = lds + ((q + 2) % 3) * CHUNKB;   // (q-1)%3; q=0 -> buf2 (mini)
#pragma unroll
        for (int jj = 0; jj < 2; ++jj) {
            f32x16 a0 = bi0, a1 = bi1;
#pragma unroll
            for (int kh = 0; kh < 3; ++kh) {
                const int t = jj + kh;                  // compile-time 0..3
                const int p_rel = 2 * wid + t;          // row within extended quarter
                const char* rb;
                if (p_rel < 2) {                        // only wid==0, t<2 (uniform branch)
                    rb = (q == 0) ? prevb + p_rel * ROWB        // mini slots 0,1
                                  : prevb + (6 + p_rel) * ROWB; // prev chunk slots 6,7
                } else {
                    rb = curb + (p_rel - 2) * ROWB;
                }
#pragma unroll
                for (int kw = 0; kw < 3; ++kw) {
                    f32x4 lo = *reinterpret_cast<const f32x4*>(rb + colv[kw]);
                    f32x4 hi = *reinterpret_cast<const f32x4*>(rb + colh[kw]);
                    unsigned d0, d1, d2, d3;
                    asm("v_cvt_pk_bf16_f32 %0, %1, %2" : "=v"(d0) : "v"(lo[0]), "v"(lo[1]));
                    asm("v_cvt_pk_bf16_f32 %0, %1, %2" : "=v"(d1) : "v"(lo[2]), "v"(lo[3]));
                    asm("v_cvt_pk_bf16_f32 %0, %1, %2" : "=v"(d2) : "v"(hi[0]), "v"(hi[1]));
                    asm("v_cvt_pk_bf16_f32 %0, %1, %2" : "=v"(d3) : "v"(hi[2]), "v"(hi[3]));
                    union { unsigned u[4]; short8 s; } fb = {{d0, d1, d2, d3}};
                    a0 = __builtin_amdgcn_mfma_f32_32x32x16_bf16(wf[kh * 3 + kw][0], fb.s, a0, 0, 0, 0);
                    a1 = __builtin_amdgcn_mfma_f32_32x32x16_bf16(wf[kh * 3 + kw][1], fb.s, a1, 0, 0, 0);
                }
            }
            // min over 32 in-lane channel rows, then xor32 across ci-halves
            float v = fminf(a0[0], a1[0]);
#pragma unroll
            for (int r = 1; r < 16; ++r) v = fminf(v, fminf(a0[r], a1[r]));
            v = fminf(v, __shfl_xor(v, 32, 64));
            const float y  = dtanh2(v);
            const int   oh = oh0 + 8 * q + 2 * wid + jj;
            const int   ow = ow0 + px;
            if (lane < 32 && oh < OHH && ow < OWW)
                out[((size_t)n * OHH + oh) * OWW + ow] = y;
        }
        asm volatile("s_waitcnt vmcnt(0)" ::: "memory");  // drain refill(q+1) (+stores)
        __syncthreads();
    }
}

extern "C" void kernel_launch(void* const* d_in, const int* in_sizes, int n_in,
                              void* d_out, int out_size, void* d_ws, size_t ws_size,
                              hipStream_t stream) {
    const float* x = (const float*)d_in[0];
    const float* w = (const float*)d_in[1];
    const float* b = (const float*)d_in[2];
    float* out     = (float*)d_out;
    ushort* wfrag  = (ushort*)d_ws;          // 18 KiB

    prep_weights<<<36, 256, 0, stream>>>(w, wfrag);
    dim3 grid(8, 8, 32);                     // (owT, ohT, n), 32x32 tiles
    conv_min_tanh<<<grid, dim3(256, 1, 1), 0, stream>>>(x, wfrag, b, out);
}

// Round 13
// 57.664 us; speedup vs baseline: 1.7368x; 1.7368x over previous
//
#include <hip/hip_runtime.h>
#include <hip/hip_bf16.h>

typedef __attribute__((ext_vector_type(8)))  short short8;
typedef __attribute__((ext_vector_type(4)))  float f32x4;
typedef __attribute__((ext_vector_type(16))) float f32x16;

#define CIN   16
#define HH    256
#define WW    256
#define OHH   254
#define OWW   254

// LDS patch: [2 cihalf][34 h][36 w][8 ci] bf16, 16B cells (R7-proven:
// px stride 16B -> conflict-free b128 reads). ci-half stride padded +16B.
#define HSTR   (36 * 8)              // 288 ushorts per h row
#define HALF   (34 * HSTR + 8)       // 9800 ushorts per ci-half
// total 39,200 B -> 4 blocks/CU

__device__ __forceinline__ ushort f2bf(float f) {
    unsigned u = __builtin_bit_cast(unsigned, f);
    unsigned r = (u + 0x7fffu + ((u >> 16) & 1u)) >> 16;
    return (ushort)r;
}

// fast tanh(tanh(x)): exp2-based (verified absmax 3.9e-3 in R1-R12)
__device__ __forceinline__ float dtanh2(float x) {
    const float K = 2.8853900817779268f;   // 2*log2(e)
    float xc = fminf(fmaxf(x, -9.0f), 9.0f);
    float e1 = __builtin_amdgcn_exp2f(K * xc);
    float t1 = 1.0f - 2.0f * __builtin_amdgcn_rcpf(e1 + 1.0f);
    float e2 = __builtin_amdgcn_exp2f(K * t1);
    return 1.0f - 2.0f * __builtin_amdgcn_rcpf(e2 + 1.0f);
}

// Weights fp32 OIHW [64][16][3][3] -> 32x32x16 A-fragments (R9-proven):
// wfrag[tap][j][lane][r]: channel row = j*32+(lane&31), ci = 8*(lane>>5)+r.
__global__ void prep_weights(const float* __restrict__ wsrc, ushort* __restrict__ wfrag) {
    int idx = blockIdx.x * 256 + threadIdx.x;
    if (idx >= 9216) return;
    int r    = idx & 7;
    int lane = (idx >> 3) & 63;
    int j    = (idx >> 9) & 1;
    int tap  = idx >> 10;                 // 0..8
    int ci   = 8 * (lane >> 5) + r;
    int co   = j * 32 + (lane & 31);
    int kh   = tap / 3, kw = tap - 3 * kh;
    wfrag[idx] = f2bf(wsrc[(co * CIN + ci) * 9 + kh * 3 + kw]);
}

// j-split: each wave owns ONE 32-channel tile (wf[9]=36 regs) and 16 rows.
// Peak live ~110 regs -> (256,4) cap 128 holds without spilling (WRITE_SIZE
// is the tripwire; R2/R6 lesson: never cap below the working set).
__global__ __launch_bounds__(256, 4) void conv_min_tanh(
        const float* __restrict__ x, const ushort* __restrict__ wfrag,
        const float* __restrict__ bias, float* __restrict__ out) {
    __shared__ ushort lds[2 * HALF];         // 39,200 B

    const int tid = threadIdx.x;
    const int n   = blockIdx.z;
    const int oh0 = blockIdx.y * 32;
    const int ow0 = blockIdx.x * 32;
    const int HW  = HH * WW;

    // ---- stage 34x34x16ci patch: float4 quad loads + cvt_pk + b64 LDS writes ----
    // slot = (hp 0..33, ciq 0..3, w4 0..8)  (R7-proven staging)
    const float* xb = x + (size_t)n * CIN * HW;
    auto stage_pos = [&](int pos) {
        int hp  = pos / 36;
        int r2  = pos - hp * 36;
        int ciq = r2 / 9;
        int w4  = r2 - ciq * 9;
        int hg  = min(oh0 + hp, HH - 1);     // clamped edges; outputs masked at store
        int wg  = min(ow0 + 4 * w4, WW - 4); // keeps 16B alignment
        const float* src = xb + (size_t)(ciq * 4) * HW + hg * WW + wg;
        f32x4 v0 = *reinterpret_cast<const f32x4*>(src);
        f32x4 v1 = *reinterpret_cast<const f32x4*>(src + HW);
        f32x4 v2 = *reinterpret_cast<const f32x4*>(src + 2 * HW);
        f32x4 v3 = *reinterpret_cast<const f32x4*>(src + 3 * HW);
        ushort* dst = &lds[(ciq >> 1) * HALF + (hp * 36 + 4 * w4) * 8 + (ciq & 1) * 4];
#pragma unroll
        for (int e = 0; e < 4; ++e) {
            unsigned lo, hi;
            asm("v_cvt_pk_bf16_f32 %0, %1, %2" : "=v"(lo) : "v"(v0[e]), "v"(v1[e]));
            asm("v_cvt_pk_bf16_f32 %0, %1, %2" : "=v"(hi) : "v"(v2[e]), "v"(v3[e]));
            uint2 pk; pk.x = lo; pk.y = hi;
            *reinterpret_cast<uint2*>(dst + e * 8) = pk;
        }
    };
#pragma unroll
    for (int it = 0; it < 4; ++it) stage_pos(tid + it * 256);
    if (tid < 1224 - 1024) stage_pos(tid + 1024);

    const int lane  = tid & 63;
    const int wid   = tid >> 6;
    const int jw    = wid & 1;           // channel tile (32 channels)
    const int rh    = wid >> 1;          // row half: rows rh*16 .. rh*16+15
    const int px    = lane & 31;         // output pixel column
    const int khalf = lane >> 5;         // ci-half

    // ---- this wave's weight tile (A-operand): 36 VGPRs ----
    short8 wf[9];
#pragma unroll
    for (int tap = 0; tap < 9; ++tap)
        wf[tap] = *reinterpret_cast<const short8*>(wfrag + ((tap * 2 + jw) * 64 + lane) * 8);
    // bias -> acc init. D row (channel-in-tile) = (r&3) + 8*(r>>2) + 4*khalf.
    f32x16 bi;
#pragma unroll
    for (int q4 = 0; q4 < 4; ++q4) {
        f32x4 b = *reinterpret_cast<const f32x4*>(bias + jw * 32 + 4 * khalf + 8 * q4);
#pragma unroll
        for (int s = 0; s < 4; ++s) bi[q4 * 4 + s] = b[s];
    }
    // B-fragment LDS bases per tap (conflict-free: 16B cells, px-stride 16B)
    const ushort* bp[9];
#pragma unroll
    for (int tap = 0; tap < 9; ++tap) {
        int kh = tap / 3, kw = tap - 3 * kh;
        bp[tap] = &lds[khalf * HALF + (rh * 16 + kh) * HSTR + (px + kw) * 8];
    }

    __syncthreads();                         // patch ready

    // ---- 16 rows per wave: 9 b128 reads + 9 MFMA per row; row-min into regs ----
    float mv[16];
#pragma unroll
    for (int i = 0; i < 16; ++i) {
        f32x16 a = bi;
#pragma unroll
        for (int tap = 0; tap < 9; ++tap) {
            short8 b = *reinterpret_cast<const short8*>(bp[tap] + i * HSTR);
            a = __builtin_amdgcn_mfma_f32_32x32x16_bf16(wf[tap], b, a, 0, 0, 0);
        }
        float v = a[0];
#pragma unroll
        for (int r = 1; r < 16; ++r) v = fminf(v, a[r]);
        v = fminf(v, __shfl_xor(v, 32, 64));   // combine ci-half lanes (rows 4-7 mod 8)
        mv[i] = v;                             // min over this wave's 32 channels
    }

    __syncthreads();                         // all patch reads done -> patch reusable

    // ---- write per-j min plane [2][32][32] bf16 into (dead) patch LDS ----
    if (lane < 32) {
#pragma unroll
        for (int i = 0; i < 16; ++i)
            lds[(jw * 32 + rh * 16 + i) * 32 + px] = f2bf(mv[i]);
    }
    __syncthreads();

    // ---- final: 4 px per thread: min(j0,j1), double-tanh, float4 store ----
    const int row = tid >> 3, px4 = (tid & 7) * 4;
    uint2 p0 = *reinterpret_cast<const uint2*>(&lds[(     row) * 32 + px4]);
    uint2 p1 = *reinterpret_cast<const uint2*>(&lds[(32 + row) * 32 + px4]);
    f32x4 y;
#pragma unroll
    for (int e = 0; e < 4; ++e) {
        unsigned w0 = (e < 2) ? p0.x : p0.y;
        unsigned w1 = (e < 2) ? p1.x : p1.y;
        float f0 = __builtin_bit_cast(float, (e & 1) ? (w0 & 0xffff0000u) : (w0 << 16));
        float f1 = __builtin_bit_cast(float, (e & 1) ? (w1 & 0xffff0000u) : (w1 << 16));
        y[e] = dtanh2(fminf(f0, f1));
    }
    const int oh = oh0 + row, ow = ow0 + px4;
    if (oh < OHH) {
        float* op = &out[((size_t)n * OHH + oh) * OWW + ow];
        if (ow + 3 < OWW) {
            *reinterpret_cast<f32x4*>(op) = y;
        } else {
#pragma unroll
            for (int e = 0; e < 4; ++e)
                if (ow + e < OWW) op[e] = y[e];
        }
    }
}

extern "C" void kernel_launch(void* const* d_in, const int* in_sizes, int n_in,
                              void* d_out, int out_size, void* d_ws, size_t ws_size,
                              hipStream_t stream) {
    const float* x = (const float*)d_in[0];
    const float* w = (const float*)d_in[1];
    const float* b = (const float*)d_in[2];
    float* out     = (float*)d_out;
    ushort* wfrag  = (ushort*)d_ws;          // 18 KiB

    prep_weights<<<36, 256, 0, stream>>>(w, wfrag);
    dim3 grid(8, 8, 32);                     // (owT, ohT, n), 32x32 tiles
    conv_min_tanh<<<grid, dim3(256, 1, 1), 0, stream>>>(x, wfrag, b, out);
}

// Round 14
// 55.152 us; speedup vs baseline: 1.8159x; 1.0456x over previous
//
#include <hip/hip_runtime.h>
#include <hip/hip_bf16.h>

typedef __attribute__((ext_vector_type(8)))  short short8;
typedef __attribute__((ext_vector_type(4)))  float f32x4;
typedef __attribute__((ext_vector_type(16))) float f32x16;

#define CIN   16
#define HH    256
#define WW    256
#define OHH   254
#define OWW   254

// LDS patch: [2 cihalf][34 h][36 w][8 ci] bf16, 16B cells (R7/R13-proven:
// px stride 16B -> conflict-free b128 reads). ci-half stride padded +16B.
#define HSTR   (36 * 8)              // 288 ushorts per h row
#define HALF   (34 * HSTR + 8)       // 9800 ushorts per ci-half

__device__ __forceinline__ ushort f2bf(float f) {
    unsigned u = __builtin_bit_cast(unsigned, f);
    unsigned r = (u + 0x7fffu + ((u >> 16) & 1u)) >> 16;
    return (ushort)r;
}

// fast tanh(tanh(x)): exp2-based (verified absmax 3.9e-3 in R1-R13)
__device__ __forceinline__ float dtanh2(float x) {
    const float K = 2.8853900817779268f;   // 2*log2(e)
    float xc = fminf(fmaxf(x, -9.0f), 9.0f);
    float e1 = __builtin_amdgcn_exp2f(K * xc);
    float t1 = 1.0f - 2.0f * __builtin_amdgcn_rcpf(e1 + 1.0f);
    float e2 = __builtin_amdgcn_exp2f(K * t1);
    return 1.0f - 2.0f * __builtin_amdgcn_rcpf(e2 + 1.0f);
}

// Weights fp32 OIHW [64][16][3][3] -> 32x32x16 A-fragments (R9-proven):
// wfrag[tap][j][lane][r]: channel row = j*32+(lane&31), ci = 8*(lane>>5)+r.
__global__ void prep_weights(const float* __restrict__ wsrc, ushort* __restrict__ wfrag) {
    int idx = blockIdx.x * 256 + threadIdx.x;
    if (idx >= 9216) return;
    int r    = idx & 7;
    int lane = (idx >> 3) & 63;
    int j    = (idx >> 9) & 1;
    int tap  = idx >> 10;                 // 0..8
    int ci   = 8 * (lane >> 5) + r;
    int co   = j * 32 + (lane & 31);
    int kh   = tap / 3, kw = tap - 3 * kh;
    wfrag[idx] = f2bf(wsrc[(co * CIN + ci) * 9 + kh * 3 + kw]);
}

// Chunk-pipelined j-split kernel. Live set ~130 regs at (256,3)=170 cap.
// R2/R6/R10 lesson: never cap below the working set (spill -> WRITE_SIZE).
__global__ __launch_bounds__(256, 3) void conv_min_tanh(
        const float* __restrict__ x, const ushort* __restrict__ wfrag,
        const float* __restrict__ bias, float* __restrict__ out) {
    __shared__ ushort lds[2 * HALF];         // 39,200 B patch
    __shared__ ushort mp[2][32][32];         // 4,096 B per-j min planes

    const int tid = threadIdx.x;
    const int n   = blockIdx.z;
    const int oh0 = blockIdx.y * 32;
    const int ow0 = blockIdx.x * 32;
    const int HW  = HH * WW;
    const float* xb = x + (size_t)n * CIN * HW;

    // ---- prologue: stage patch rows 0..9 inline (R13-style) ----
    auto stage0 = [&](int pos) {             // pos = hp*36 + ciq*9 + w4, hp 0..9
        int hp  = pos / 36;
        int r2  = pos - hp * 36;
        int ciq = r2 / 9;
        int w4  = r2 - ciq * 9;
        int hg  = min(oh0 + hp, HH - 1);
        int wg  = min(ow0 + 4 * w4, WW - 4);
        const float* src = xb + (size_t)(ciq * 4) * HW + hg * WW + wg;
        f32x4 v0 = *reinterpret_cast<const f32x4*>(src);
        f32x4 v1 = *reinterpret_cast<const f32x4*>(src + HW);
        f32x4 v2 = *reinterpret_cast<const f32x4*>(src + 2 * HW);
        f32x4 v3 = *reinterpret_cast<const f32x4*>(src + 3 * HW);
        ushort* dst = &lds[(ciq >> 1) * HALF + (hp * 36 + 4 * w4) * 8 + (ciq & 1) * 4];
#pragma unroll
        for (int e = 0; e < 4; ++e) {
            unsigned lo, hi;
            asm("v_cvt_pk_bf16_f32 %0, %1, %2" : "=v"(lo) : "v"(v0[e]), "v"(v1[e]));
            asm("v_cvt_pk_bf16_f32 %0, %1, %2" : "=v"(hi) : "v"(v2[e]), "v"(v3[e]));
            uint2 pk; pk.x = lo; pk.y = hi;
            *reinterpret_cast<uint2*>(dst + e * 8) = pk;
        }
    };
    stage0(tid);
    if (tid < 104) stage0(tid + 256);        // 360 positions (10 rows)

    // ---- this thread's chunk-stage positions (8-row chunks, 288 positions) ----
    // pos0 = tid; pos1 = 256+tid for tid<32 (lr1==7, rem1 = 4+tid)
    const int lr0  = tid / 36;
    const int rm0  = tid - lr0 * 36;
    const int ciq0 = rm0 / 9;
    const int w40  = rm0 - ciq0 * 9;
    const int wg0  = min(ow0 + 4 * w40, WW - 4);
    const int gc0  = ciq0 * 4 * HW + wg0;                // global col+plane (dwords)
    const bool two = (tid < 32);
    const int ciq1 = (4 + tid) / 9;                      // lr1 = 7
    const int w41  = (4 + tid) - ciq1 * 9;
    const int wg1  = min(ow0 + 4 * w41, WW - 4);
    const int gc1  = ciq1 * 4 * HW + wg1;
    // LDS dst offsets, minus the row term (row added per chunk)
    const int ld0  = (ciq0 >> 1) * HALF + (4 * w40) * 8 + (ciq0 & 1) * 4;
    const int ld1  = (ciq1 >> 1) * HALF + (4 * w41) * 8 + (ciq1 & 1) * 4;

    const int lane  = tid & 63;
    const int wid   = tid >> 6;
    const int jw    = wid & 1;           // channel tile (32 channels)
    const int rq    = wid >> 1;          // row quad within chunk
    const int px    = lane & 31;
    const int khalf = lane >> 5;

    // ---- weight tile (A-operand), bias ----
    short8 wf[9];
#pragma unroll
    for (int tap = 0; tap < 9; ++tap)
        wf[tap] = *reinterpret_cast<const short8*>(wfrag + ((tap * 2 + jw) * 64 + lane) * 8);
    f32x16 bi;                           // D row = (r&3)+8*(r>>2)+4*khalf
#pragma unroll
    for (int q4 = 0; q4 < 4; ++q4) {
        f32x4 b = *reinterpret_cast<const f32x4*>(bias + jw * 32 + 4 * khalf + 8 * q4);
#pragma unroll
        for (int s = 0; s < 4; ++s) bi[q4 * 4 + s] = b[s];
    }
    // single LDS base; all tap/row displacements are compile-time immediates
    const ushort* bptr = &lds[khalf * HALF + (rq * 4) * HSTR + px * 8];

    __syncthreads();                     // rows 0..9 ready

    f32x4 ra0, ra1, ra2, ra3, rb0, rb1, rb2, rb3;   // in-flight chunk (<=32 regs)

    // ---- chunk loop: issue(q+1) -> compute(q) -> wait+write(q+1) -> barrier ----
#pragma unroll
    for (int q = 0; q < 4; ++q) {
        if (q < 3) {                     // issue chunk q+1 (rows 8q+10 .. 8q+17)
            const int c = q + 1;
            {
                int hg = min(oh0 + 8 * c + 2 + lr0, HH - 1);
                const float* s = xb + gc0 + hg * WW;
                asm volatile("global_load_dwordx4 %0, %1, off" : "=v"(ra0) : "v"(s) : "memory");
                asm volatile("global_load_dwordx4 %0, %1, off" : "=v"(ra1) : "v"(s + HW) : "memory");
                asm volatile("global_load_dwordx4 %0, %1, off" : "=v"(ra2) : "v"(s + 2 * HW) : "memory");
                asm volatile("global_load_dwordx4 %0, %1, off" : "=v"(ra3) : "v"(s + 3 * HW) : "memory");
            }
            if (two) {
                int hg = min(oh0 + 8 * c + 2 + 7, HH - 1);
                const float* s = xb + gc1 + hg * WW;
                asm volatile("global_load_dwordx4 %0, %1, off" : "=v"(rb0) : "v"(s) : "memory");
                asm volatile("global_load_dwordx4 %0, %1, off" : "=v"(rb1) : "v"(s + HW) : "memory");
                asm volatile("global_load_dwordx4 %0, %1, off" : "=v"(rb2) : "v"(s + 2 * HW) : "memory");
                asm volatile("global_load_dwordx4 %0, %1, off" : "=v"(rb3) : "v"(s + 3 * HW) : "memory");
            }
        }

        // ---- compute chunk q: rows 8q+rq*4 .. +3 ----
#pragma unroll
        for (int i = 0; i < 4; ++i) {
            f32x16 a = bi;
#pragma unroll
            for (int kh = 0; kh < 3; ++kh)
#pragma unroll
                for (int kw = 0; kw < 3; ++kw) {
                    short8 b = *reinterpret_cast<const short8*>(
                        bptr + (8 * q + i + kh) * HSTR + kw * 8);
                    a = __builtin_amdgcn_mfma_f32_32x32x16_bf16(wf[kh * 3 + kw], b, a, 0, 0, 0);
                }
            float v = a[0];
#pragma unroll
            for (int r = 1; r < 16; ++r) v = fminf(v, a[r]);
            v = fminf(v, __shfl_xor(v, 32, 64));
            if (lane < 32) mp[jw][8 * q + rq * 4 + i][px] = f2bf(v);
        }

        if (q < 3) {                     // drain the single outstanding chunk, write it
            asm volatile("s_waitcnt vmcnt(0)" ::: "memory");
            const int c = q + 1;
            {
                ushort* dst = &lds[ld0 + ((8 * c + 2 + lr0) * 36) * 8];
#pragma unroll
                for (int e = 0; e < 4; ++e) {
                    unsigned lo, hi;
                    asm("v_cvt_pk_bf16_f32 %0, %1, %2" : "=v"(lo) : "v"(ra0[e]), "v"(ra1[e]));
                    asm("v_cvt_pk_bf16_f32 %0, %1, %2" : "=v"(hi) : "v"(ra2[e]), "v"(ra3[e]));
                    uint2 pk; pk.x = lo; pk.y = hi;
                    *reinterpret_cast<uint2*>(dst + e * 8) = pk;
                }
            }
            if (two) {
                ushort* dst = &lds[ld1 + ((8 * c + 2 + 7) * 36) * 8];
#pragma unroll
                for (int e = 0; e < 4; ++e) {
                    unsigned lo, hi;
                    asm("v_cvt_pk_bf16_f32 %0, %1, %2" : "=v"(lo) : "v"(rb0[e]), "v"(rb1[e]));
                    asm("v_cvt_pk_bf16_f32 %0, %1, %2" : "=v"(hi) : "v"(rb2[e]), "v"(rb3[e]));
                    uint2 pk; pk.x = lo; pk.y = hi;
                    *reinterpret_cast<uint2*>(dst + e * 8) = pk;
                }
            }
            __syncthreads();
        }
    }

    __syncthreads();                     // mp planes visible

    // ---- final: 4 px per thread: min(j0,j1), double-tanh, float4 store ----
    const int row = tid >> 3, px4 = (tid & 7) * 4;
    uint2 p0 = *reinterpret_cast<const uint2*>(&mp[0][row][px4]);
    uint2 p1 = *reinterpret_cast<const uint2*>(&mp[1][row][px4]);
    f32x4 y;
#pragma unroll
    for (int e = 0; e < 4; ++e) {
        unsigned w0 = (e < 2) ? p0.x : p0.y;
        unsigned w1 = (e < 2) ? p1.x : p1.y;
        float f0 = __builtin_bit_cast(float, (e & 1) ? (w0 & 0xffff0000u) : (w0 << 16));
        float f1 = __builtin_bit_cast(float, (e & 1) ? (w1 & 0xffff0000u) : (w1 << 16));
        y[e] = dtanh2(fminf(f0, f1));
    }
    const int oh = oh0 + row, ow = ow0 + px4;
    if (oh < OHH) {
        float* op = &out[((size_t)n * OHH + oh) * OWW + ow];
        if (ow + 3 < OWW) {
            *reinterpret_cast<f32x4*>(op) = y;
        } else {
#pragma unroll
            for (int e = 0; e < 4; ++e)
                if (ow + e < OWW) op[e] = y[e];
        }
    }
}

extern "C" void kernel_launch(void* const* d_in, const int* in_sizes, int n_in,
                              void* d_out, int out_size, void* d_ws, size_t ws_size,
                              hipStream_t stream) {
    const float* x = (const float*)d_in[0];
    const float* w = (const float*)d_in[1];
    const float* b = (const float*)d_in[2];
    float* out     = (float*)d_out;
    ushort* wfrag  = (ushort*)d_ws;          // 18 KiB

    prep_weights<<<36, 256, 0, stream>>>(w, wfrag);
    dim3 grid(8, 8, 32);                     // (owT, ohT, n), 32x32 tiles
    conv_min_tanh<<<grid, dim3(256, 1, 1), 0, stream>>>(x, wfrag, b, out);
}